// Round 1
// baseline (178.829 us; speedup 1.0000x reference)
//
#include <hip/hip_runtime.h>
#include <hip/hip_bf16.h>

// GegenbauerKAN layer == fused BF16-MFMA GEMM, M=16384 N=512 K=4096 (i*8+d).
// ALPHA=1 => Chebyshev-U recurrence: C_{n+1} = 2t*C_n - C_{n-1}, t = tanh(x).
// R2: 512 blocks (BM=128,BN=128, 256 thr); coeffs pre-converted to bf16 in d_ws,
//     W staged via global_load_lds(16B).
// R3: depth-1 software pipeline. Double-buffer As+Ws; prefetch W[it+1] (async
//     global_load_lds) and x[it+1] at the top of each iter, MFMA on cur in the
//     middle, feature-gen for it+1 at the bottom, ONE barrier per iter (was 2).
//     Rationale: rocprof showed MfmaUtil 27 + VALUBusy 40 with 33% all-wave
//     stall — the per-iter vmcnt(0)+barrier drain of W loads issued right
//     before the barrier. LDS 34.8->69.6KB: still 2 blocks/CU (grid-limited).

#define I_DIM 512
#define O_DIM 512
#define NDEG 8
#define BM 128
#define BN 128
#define IPB 8              // i-values per K-iteration (BK = 64)
#define LSTR 72            // As row stride in bf16 elems (144 B, banks balanced)
#define KITERS (I_DIM / IPB)
#define NTHREADS 256
#define W_ELEMS (I_DIM * O_DIM * NDEG)   // 2,097,152

typedef __attribute__((ext_vector_type(8))) short s8v;    // MFMA A/B frag (8 bf16)
typedef __attribute__((ext_vector_type(4))) float f32x4;  // MFMA C/D frag
typedef unsigned short u16;

__device__ __forceinline__ unsigned pack2bf(float a, float b) {
    // RNE fp32->bf16 for both, packed (a in low half, b in high half)
    unsigned ua = __float_as_uint(a), ub = __float_as_uint(b);
    ua += 0x7fffu + ((ua >> 16) & 1u);
    ub += 0x7fffu + ((ub >> 16) & 1u);
    return (ua >> 16) | (ub & 0xffff0000u);
}

__device__ __forceinline__ float fast_tanh(float v) {
    float e = __expf(v + v);
    float r = __builtin_amdgcn_rcpf(e + 1.0f);
    return 1.0f - (r + r);
}

// ---- one-shot coeffs fp32 -> bf16 into workspace (re-run every call; ws is re-poisoned)
extern "C" __global__ __launch_bounds__(256)
void cvt_w(const float* __restrict__ cf, u16* __restrict__ wbf) {
    const size_t idx = ((size_t)blockIdx.x * 256 + threadIdx.x) * 4;
    const float4 v = *reinterpret_cast<const float4*>(cf + idx);
    unsigned* dst = reinterpret_cast<unsigned*>(wbf + idx);
    dst[0] = pack2bf(v.x, v.y);
    dst[1] = pack2bf(v.z, v.w);
}

template <bool PRECONV>
__global__ __launch_bounds__(NTHREADS, 2)
void gegen_gemm(const float* __restrict__ x,
                const float* __restrict__ cf,
                const u16* __restrict__ wbf,
                float* __restrict__ out)
{
    __shared__ u16 As[2][BM * LSTR];          // [buf][m][k] bf16, padded rows
    __shared__ u16 Ws[2][IPB * BN * NDEG];    // [buf][i_local][o][d] bf16, UNPADDED (global_load_lds dst)

    const int tid  = threadIdx.x;
    const int lane = tid & 63;
    const int wave = tid >> 6;             // 0..3, 2x2 grid of 64x64 wave tiles
    const int fm   = lane & 15;
    const int fq   = lane >> 4;
    const int wr   = (wave >> 1) << 6;     // 0 / 64
    const int wc   = (wave & 1) << 6;      // 0 / 64

    const int bm0 = blockIdx.y * BM;
    const int bn0 = blockIdx.x * BN;

    // A staging map: 128 rows x 8 i = 256 float4, one per thread
    const int ar = tid >> 1;               // row 0..127
    const int ai = (tid & 1) << 2;         // i_local 0 or 4
    const float* xp = x + (size_t)(bm0 + ar) * I_DIM + ai;

    f32x4 acc[4][4];
#pragma unroll
    for (int a = 0; a < 4; ++a)
#pragma unroll
        for (int b = 0; b < 4; ++b)
            acc[a][b] = (f32x4){0.0f, 0.0f, 0.0f, 0.0f};

    // ---- W stage: 16 KiB tile into Ws[buf] ----
    auto stage_w = [&](int it, int buf) {
        if (PRECONV) {
            // 16 wave-chunks of 1 KiB; 4 chunks per wave.
            const u16* wsrc = wbf + ((size_t)(it * IPB) * O_DIM + bn0) * NDEG;
#pragma unroll
            for (int q = 0; q < 4; ++q) {
                const int c    = wave * 4 + q;   // 0..15
                const int il   = c >> 1;
                const int half = c & 1;
                const u16* src = wsrc + ((size_t)il * O_DIM + half * 64 + lane) * NDEG;
                u16* dst = &Ws[buf][(il * BN + half * 64) * NDEG];  // wave-uniform base
                __builtin_amdgcn_global_load_lds(
                    (const __attribute__((address_space(1))) void*)src,
                    (__attribute__((address_space(3))) void*)dst, 16, 0, 0);
            }
        } else {
            // fallback: VALU cvt staging (ws too small)
#pragma unroll
            for (int jj = 0; jj < 4; ++jj) {
                const int p  = jj * NTHREADS + tid;   // 0..1023
                const int il = p >> 7;
                const int o  = p & 127;
                const float* src = cf + ((size_t)(it * IPB + il) * O_DIM + bn0 + o) * NDEG;
                const float4 w0 = reinterpret_cast<const float4*>(src)[0];
                const float4 w1 = reinterpret_cast<const float4*>(src)[1];
                union { s8v s; unsigned u[4]; } pk;
                pk.u[0] = pack2bf(w0.x, w0.y);
                pk.u[1] = pack2bf(w0.z, w0.w);
                pk.u[2] = pack2bf(w1.x, w1.y);
                pk.u[3] = pack2bf(w1.z, w1.w);
                *reinterpret_cast<s8v*>(&Ws[buf][(il * BN + o) * NDEG]) = pk.s;
            }
        }
    };

    // ---- A stage: tanh -> Chebyshev-U -> bf16 -> LDS (buf) ----
    auto stage_a = [&](float4 xv, int buf) {
        const float vv[4] = {xv.x, xv.y, xv.z, xv.w};
#pragma unroll
        for (int j = 0; j < 4; ++j) {
            const float t  = fast_tanh(vv[j]);
            const float t2 = t + t;
            const float c1 = t2;
            const float c2 = t2 * c1 - 1.0f;
            const float c3 = t2 * c2 - c1;
            const float c4 = t2 * c3 - c2;
            const float c5 = t2 * c4 - c3;
            const float c6 = t2 * c5 - c4;
            const float c7 = t2 * c6 - c5;
            union { s8v s; unsigned u[4]; } pk;
            pk.u[0] = pack2bf(1.0f, c1);
            pk.u[1] = pack2bf(c2, c3);
            pk.u[2] = pack2bf(c4, c5);
            pk.u[3] = pack2bf(c6, c7);
            *reinterpret_cast<s8v*>(&As[buf][ar * LSTR + (ai + j) * NDEG]) = pk.s;
        }
    };

    // ---- compute: 2 k-chunks of 32, 4x4 of mfma 16x16x32 on buffer buf ----
    auto compute = [&](int buf) {
#pragma unroll
        for (int kc = 0; kc < 2; ++kc) {
            s8v afr[4], bfr[4];
#pragma unroll
            for (int tm = 0; tm < 4; ++tm)
                afr[tm] = *reinterpret_cast<const s8v*>(
                    &As[buf][(wr + tm * 16 + fm) * LSTR + kc * 32 + fq * 8]);
#pragma unroll
            for (int tn = 0; tn < 4; ++tn)
                bfr[tn] = *reinterpret_cast<const s8v*>(
                    &Ws[buf][((kc * 4 + fq) * BN + wc + tn * 16 + fm) * NDEG]);
#pragma unroll
            for (int tm = 0; tm < 4; ++tm)
#pragma unroll
                for (int tn = 0; tn < 4; ++tn)
                    acc[tm][tn] = __builtin_amdgcn_mfma_f32_16x16x32_bf16(
                        afr[tm], bfr[tn], acc[tm][tn], 0, 0, 0);
        }
    };

    // ---- prologue: fill buffer 0 ----
    stage_w(0, 0);
    stage_a(*reinterpret_cast<const float4*>(xp), 0);
    __syncthreads();

    // ---- pipelined main loop: ONE barrier per iter ----
    int cur = 0;
    for (int it = 0; it < KITERS - 1; ++it) {
        const int nxt = cur ^ 1;
        stage_w(it + 1, nxt);                                   // async, waited at barrier
        const float4 xv = *reinterpret_cast<const float4*>(xp + (it + 1) * IPB);
        compute(cur);                                           // hides load latency
        stage_a(xv, nxt);
        __syncthreads();
        cur = nxt;
    }
    compute(cur);   // last tile, no barrier needed

    // ---- epilogue: C/D col=lane&15, row=fq*4+reg ----
#pragma unroll
    for (int tm = 0; tm < 4; ++tm) {
#pragma unroll
        for (int tn = 0; tn < 4; ++tn) {
            const int row = bm0 + wr + tm * 16 + fq * 4;
            const int col = bn0 + wc + tn * 16 + fm;
#pragma unroll
            for (int r = 0; r < 4; ++r)
                out[(size_t)(row + r) * O_DIM + col] = acc[tm][tn][r];
        }
    }
}

extern "C" void kernel_launch(void* const* d_in, const int* in_sizes, int n_in,
                              void* d_out, int out_size, void* d_ws, size_t ws_size,
                              hipStream_t stream) {
    const float* x  = (const float*)d_in[0];
    const float* cf = (const float*)d_in[1];
    float* out = (float*)d_out;
    const int M = in_sizes[0] / I_DIM;            // 16384
    dim3 grid(O_DIM / BN, M / BM);                // (4, 128) = 512 blocks
    dim3 block(NTHREADS, 1, 1);

    if (ws_size >= (size_t)W_ELEMS * sizeof(u16)) {
        u16* wbf = (u16*)d_ws;
        cvt_w<<<W_ELEMS / 1024, 256, 0, stream>>>(cf, wbf);
        gegen_gemm<true><<<grid, block, 0, stream>>>(x, cf, wbf, out);
    } else {
        gegen_gemm<false><<<grid, block, 0, stream>>>(x, cf, nullptr, out);
    }
}

// Round 2
// 167.420 us; speedup vs baseline: 1.0681x; 1.0681x over previous
//
#include <hip/hip_runtime.h>
#include <hip/hip_bf16.h>

// GegenbauerKAN layer == fused BF16-MFMA GEMM, M=16384 N=512 K=4096 (i*8+d).
// ALPHA=1 => Chebyshev-U recurrence: C_{n+1} = 2t*C_n - C_{n-1}, t = tanh(x).
// R2: coeffs pre-converted to bf16 in d_ws, W staged via global_load_lds(16B).
// R3 (REVERTED): explicit dbuf pipeline was -6% (compiler already schedules;
//     VGPR 60->88 for nothing). Back to single-buffer, 2 barriers/iter.
// R4: (a) BM 128->64: grid 1024 = 4 blocks/CU (16 waves/CU) for cross-block
//     phase overlap (m114: implicit overlap needs >=3 blocks/CU; we had 2).
//     (b) bf16 packing via v_cvt_pk_bf16_f32 (1 instr per 2 floats) instead of
//     11-op integer RNE — feature VALU was ~75% of the 40% VALUBusy.

#define I_DIM 512
#define O_DIM 512
#define NDEG 8
#define BM 64
#define BN 128
#define IPB 8              // i-values per K-iteration (BK = 64)
#define LSTR 72            // As row stride in bf16 elems (144 B)
#define KITERS (I_DIM / IPB)
#define NTHREADS 256
#define W_ELEMS (I_DIM * O_DIM * NDEG)   // 2,097,152

typedef __attribute__((ext_vector_type(8))) short s8v;    // MFMA A/B frag (8 bf16)
typedef __attribute__((ext_vector_type(4))) float f32x4;  // MFMA C/D frag
typedef unsigned short u16;

__device__ __forceinline__ unsigned pack2bf(float a, float b) {
    // RNE fp32->bf16 for both, packed (a in low half, b in high half)
    unsigned ua = __float_as_uint(a), ub = __float_as_uint(b);
    ua += 0x7fffu + ((ua >> 16) & 1u);
    ub += 0x7fffu + ((ub >> 16) & 1u);
    return (ua >> 16) | (ub & 0xffff0000u);
}

// HW packed f32->bf16 (RNE): D[15:0]=bf16(lo), D[31:16]=bf16(hi). 1 VALU op.
__device__ __forceinline__ unsigned cvt_pk_bf16(float lo, float hi) {
    unsigned r;
    asm("v_cvt_pk_bf16_f32 %0, %1, %2" : "=v"(r) : "v"(lo), "v"(hi));
    return r;
}

__device__ __forceinline__ float fast_tanh(float v) {
    float e = __expf(v + v);
    float r = __builtin_amdgcn_rcpf(e + 1.0f);
    return 1.0f - (r + r);
}

// ---- one-shot coeffs fp32 -> bf16 into workspace (re-run every call; ws is re-poisoned)
extern "C" __global__ __launch_bounds__(256)
void cvt_w(const float* __restrict__ cf, u16* __restrict__ wbf) {
    const size_t idx = ((size_t)blockIdx.x * 256 + threadIdx.x) * 4;
    const float4 v = *reinterpret_cast<const float4*>(cf + idx);
    unsigned* dst = reinterpret_cast<unsigned*>(wbf + idx);
    dst[0] = cvt_pk_bf16(v.x, v.y);
    dst[1] = cvt_pk_bf16(v.z, v.w);
}

template <bool PRECONV>
__global__ __launch_bounds__(NTHREADS, 4)
void gegen_gemm(const float* __restrict__ x,
                const float* __restrict__ cf,
                const u16* __restrict__ wbf,
                float* __restrict__ out)
{
    __shared__ u16 As[BM * LSTR];          // [m][k] bf16, padded rows (9.2 KB)
    __shared__ u16 Ws[IPB * BN * NDEG];    // [i_local][o][d] bf16, UNPADDED (16 KB, global_load_lds dst)

    const int tid  = threadIdx.x;
    const int lane = tid & 63;
    const int wave = tid >> 6;             // 0..3, 2x2 grid of 32x64 wave tiles
    const int fm   = lane & 15;
    const int fq   = lane >> 4;
    const int wr   = (wave >> 1) << 5;     // 0 / 32
    const int wc   = (wave & 1) << 6;      // 0 / 64

    const int bm0 = blockIdx.y * BM;
    const int bn0 = blockIdx.x * BN;

    // A staging map: 64 rows x 8 i = 512 floats, one float2 per thread
    const int ar = tid >> 2;               // row 0..63
    const int ai = (tid & 3) << 1;         // i_local 0,2,4,6
    const float* xp = x + (size_t)(bm0 + ar) * I_DIM + ai;

    f32x4 acc[2][4];
#pragma unroll
    for (int a = 0; a < 2; ++a)
#pragma unroll
        for (int b = 0; b < 4; ++b)
            acc[a][b] = (f32x4){0.0f, 0.0f, 0.0f, 0.0f};

    for (int it = 0; it < KITERS; ++it) {
        // ---- W stage ----
        if (PRECONV) {
            // 16 KiB tile = 16 wave-chunks of 1 KiB; 4 chunks per wave.
            const u16* wsrc = wbf + ((size_t)(it * IPB) * O_DIM + bn0) * NDEG;
#pragma unroll
            for (int q = 0; q < 4; ++q) {
                const int c    = wave * 4 + q;   // 0..15
                const int il   = c >> 1;
                const int half = c & 1;
                const u16* src = wsrc + ((size_t)il * O_DIM + half * 64 + lane) * NDEG;
                u16* dst = &Ws[(il * BN + half * 64) * NDEG];  // wave-uniform base
                __builtin_amdgcn_global_load_lds(
                    (const __attribute__((address_space(1))) void*)src,
                    (__attribute__((address_space(3))) void*)dst, 16, 0, 0);
            }
        } else {
            // fallback: VALU cvt staging (ws too small)
#pragma unroll
            for (int jj = 0; jj < 4; ++jj) {
                const int p  = jj * NTHREADS + tid;   // 0..1023
                const int il = p >> 7;
                const int o  = p & 127;
                const float* src = cf + ((size_t)(it * IPB + il) * O_DIM + bn0 + o) * NDEG;
                const float4 w0 = reinterpret_cast<const float4*>(src)[0];
                const float4 w1 = reinterpret_cast<const float4*>(src)[1];
                union { s8v s; unsigned u[4]; } pk;
                pk.u[0] = cvt_pk_bf16(w0.x, w0.y);
                pk.u[1] = cvt_pk_bf16(w0.z, w0.w);
                pk.u[2] = cvt_pk_bf16(w1.x, w1.y);
                pk.u[3] = cvt_pk_bf16(w1.z, w1.w);
                *reinterpret_cast<s8v*>(&Ws[(il * BN + o) * NDEG]) = pk.s;
            }
        }

        // ---- A stage: x -> tanh -> Chebyshev-U -> bf16 -> LDS ----
        {
            const float2 xv = *reinterpret_cast<const float2*>(xp + it * IPB);
            const float vv[2] = {xv.x, xv.y};
#pragma unroll
            for (int j = 0; j < 2; ++j) {
                const float t  = fast_tanh(vv[j]);
                const float t2 = t + t;
                const float c1 = t2;
                const float c2 = t2 * c1 - 1.0f;
                const float c3 = t2 * c2 - c1;
                const float c4 = t2 * c3 - c2;
                const float c5 = t2 * c4 - c3;
                const float c6 = t2 * c5 - c4;
                const float c7 = t2 * c6 - c5;
                union { s8v s; unsigned u[4]; } pk;
                pk.u[0] = cvt_pk_bf16(1.0f, c1);
                pk.u[1] = cvt_pk_bf16(c2, c3);
                pk.u[2] = cvt_pk_bf16(c4, c5);
                pk.u[3] = cvt_pk_bf16(c6, c7);
                *reinterpret_cast<s8v*>(&As[ar * LSTR + (ai + j) * NDEG]) = pk.s;
            }
        }
        __syncthreads();

        // ---- compute: 2 k-chunks of 32, 2x4 of mfma 16x16x32 ----
#pragma unroll
        for (int kc = 0; kc < 2; ++kc) {
            s8v afr[2], bfr[4];
#pragma unroll
            for (int tm = 0; tm < 2; ++tm)
                afr[tm] = *reinterpret_cast<const s8v*>(
                    &As[(wr + tm * 16 + fm) * LSTR + kc * 32 + fq * 8]);
#pragma unroll
            for (int tn = 0; tn < 4; ++tn)
                bfr[tn] = *reinterpret_cast<const s8v*>(
                    &Ws[((kc * 4 + fq) * BN + wc + tn * 16 + fm) * NDEG]);
#pragma unroll
            for (int tm = 0; tm < 2; ++tm)
#pragma unroll
                for (int tn = 0; tn < 4; ++tn)
                    acc[tm][tn] = __builtin_amdgcn_mfma_f32_16x16x32_bf16(
                        afr[tm], bfr[tn], acc[tm][tn], 0, 0, 0);
        }
        __syncthreads();
    }

    // ---- epilogue: C/D col=lane&15, row=fq*4+reg ----
#pragma unroll
    for (int tm = 0; tm < 2; ++tm) {
#pragma unroll
        for (int tn = 0; tn < 4; ++tn) {
            const int row = bm0 + wr + tm * 16 + fq * 4;
            const int col = bn0 + wc + tn * 16 + fm;
#pragma unroll
            for (int r = 0; r < 4; ++r)
                out[(size_t)(row + r) * O_DIM + col] = acc[tm][tn][r];
        }
    }
}

extern "C" void kernel_launch(void* const* d_in, const int* in_sizes, int n_in,
                              void* d_out, int out_size, void* d_ws, size_t ws_size,
                              hipStream_t stream) {
    const float* x  = (const float*)d_in[0];
    const float* cf = (const float*)d_in[1];
    float* out = (float*)d_out;
    const int M = in_sizes[0] / I_DIM;            // 16384
    dim3 grid(O_DIM / BN, M / BM);                // (4, 256) = 1024 blocks
    dim3 block(NTHREADS, 1, 1);

    if (ws_size >= (size_t)W_ELEMS * sizeof(u16)) {
        u16* wbf = (u16*)d_ws;
        cvt_w<<<W_ELEMS / 1024, 256, 0, stream>>>(cf, wbf);
        gegen_gemm<true><<<grid, block, 0, stream>>>(x, cf, wbf, out);
    } else {
        gegen_gemm<false><<<grid, block, 0, stream>>>(x, cf, nullptr, out);
    }
}

// Round 3
// 161.349 us; speedup vs baseline: 1.1083x; 1.0376x over previous
//
#include <hip/hip_runtime.h>
#include <hip/hip_bf16.h>

// GegenbauerKAN layer == fused BF16-MFMA GEMM, M=16384 N=512 K=4096 (i*8+d).
// ALPHA=1 => Chebyshev-U recurrence: C_{n+1} = 2t*C_n - C_{n-1}, t = tanh(x).
// R2: coeffs pre-converted to bf16 in d_ws, W staged via global_load_lds(16B).
// R3 (REVERTED): explicit dbuf pipeline -6% (compiler already schedules).
// R4: BM=64 -> 1024 blocks = 4 blocks/CU; v_cvt_pk_bf16_f32 packing.
//     (100us, MfmaUtil 30, VALU 30; LDS pipe est. ~57us = largest consumer)
// R5: K-split waves. Waves (wc,kh): kh=0/1 each accumulate one K=32 half of a
//     64x64 output tile (4x4 frags, reads/MFMA 0.75->0.5, LDS reads -33%)
//     while keeping 256 thr / 4 blocks/CU / 16 waves/CU. One-time chunked
//     LDS pair-reduction (kh=1 -> kh=0) in the epilogue sums the halves.

#define I_DIM 512
#define O_DIM 512
#define NDEG 8
#define BM 64
#define BN 128
#define IPB 8              // i-values per K-iteration (BK = 64)
#define LSTR 72            // As row stride in bf16 elems (144 B)
#define KITERS (I_DIM / IPB)
#define NTHREADS 256
#define W_ELEMS (I_DIM * O_DIM * NDEG)   // 2,097,152

typedef __attribute__((ext_vector_type(8))) short s8v;    // MFMA A/B frag (8 bf16)
typedef __attribute__((ext_vector_type(4))) float f32x4;  // MFMA C/D frag
typedef unsigned short u16;

// HW packed f32->bf16 (RNE): D[15:0]=bf16(lo), D[31:16]=bf16(hi). 1 VALU op.
__device__ __forceinline__ unsigned cvt_pk_bf16(float lo, float hi) {
    unsigned r;
    asm("v_cvt_pk_bf16_f32 %0, %1, %2" : "=v"(r) : "v"(lo), "v"(hi));
    return r;
}

__device__ __forceinline__ float fast_tanh(float v) {
    float e = __expf(v + v);
    float r = __builtin_amdgcn_rcpf(e + 1.0f);
    return 1.0f - (r + r);
}

// ---- one-shot coeffs fp32 -> bf16 into workspace (re-run every call; ws is re-poisoned)
extern "C" __global__ __launch_bounds__(256)
void cvt_w(const float* __restrict__ cf, u16* __restrict__ wbf) {
    const size_t idx = ((size_t)blockIdx.x * 256 + threadIdx.x) * 4;
    const float4 v = *reinterpret_cast<const float4*>(cf + idx);
    unsigned* dst = reinterpret_cast<unsigned*>(wbf + idx);
    dst[0] = cvt_pk_bf16(v.x, v.y);
    dst[1] = cvt_pk_bf16(v.z, v.w);
}

template <bool PRECONV>
__global__ __launch_bounds__(NTHREADS, 4)
void gegen_gemm(const float* __restrict__ x,
                const float* __restrict__ cf,
                const u16* __restrict__ wbf,
                float* __restrict__ out)
{
    __shared__ u16 As[BM * LSTR];          // [m][k] bf16, padded rows (9.2 KB)
    __shared__ u16 Ws[IPB * BN * NDEG];    // [i_local][o][d] bf16, UNPADDED (16 KB, global_load_lds dst)
    __shared__ float Rs[2][16 * 64];       // epilogue pair-reduce staging (8 KB)

    const int tid  = threadIdx.x;
    const int lane = tid & 63;
    const int wave = tid >> 6;             // 0..3
    const int fm   = lane & 15;
    const int fq   = lane >> 4;
    const int kh   = wave >> 1;            // K-half: waves 0,1 -> k[0,32); 2,3 -> k[32,64)
    const int wc   = (wave & 1) << 6;      // col 0 / 64; pairs (0,2),(1,3) share output

    const int bm0 = blockIdx.y * BM;
    const int bn0 = blockIdx.x * BN;

    // A staging map: 64 rows x 8 i = 512 floats, one float2 per thread
    const int ar = tid >> 2;               // row 0..63
    const int ai = (tid & 3) << 1;         // i_local 0,2,4,6
    const float* xp = x + (size_t)(bm0 + ar) * I_DIM + ai;

    f32x4 acc[4][4];
#pragma unroll
    for (int a = 0; a < 4; ++a)
#pragma unroll
        for (int b = 0; b < 4; ++b)
            acc[a][b] = (f32x4){0.0f, 0.0f, 0.0f, 0.0f};

    for (int it = 0; it < KITERS; ++it) {
        // ---- W stage ----
        if (PRECONV) {
            // 16 KiB tile = 16 wave-chunks of 1 KiB; 4 chunks per wave.
            const u16* wsrc = wbf + ((size_t)(it * IPB) * O_DIM + bn0) * NDEG;
#pragma unroll
            for (int q = 0; q < 4; ++q) {
                const int c    = wave * 4 + q;   // 0..15
                const int il   = c >> 1;
                const int half = c & 1;
                const u16* src = wsrc + ((size_t)il * O_DIM + half * 64 + lane) * NDEG;
                u16* dst = &Ws[(il * BN + half * 64) * NDEG];  // wave-uniform base
                __builtin_amdgcn_global_load_lds(
                    (const __attribute__((address_space(1))) void*)src,
                    (__attribute__((address_space(3))) void*)dst, 16, 0, 0);
            }
        } else {
            // fallback: VALU cvt staging (ws too small)
#pragma unroll
            for (int jj = 0; jj < 4; ++jj) {
                const int p  = jj * NTHREADS + tid;   // 0..1023
                const int il = p >> 7;
                const int o  = p & 127;
                const float* src = cf + ((size_t)(it * IPB + il) * O_DIM + bn0 + o) * NDEG;
                const float4 w0 = reinterpret_cast<const float4*>(src)[0];
                const float4 w1 = reinterpret_cast<const float4*>(src)[1];
                union { s8v s; unsigned u[4]; } pk;
                pk.u[0] = cvt_pk_bf16(w0.x, w0.y);
                pk.u[1] = cvt_pk_bf16(w0.z, w0.w);
                pk.u[2] = cvt_pk_bf16(w1.x, w1.y);
                pk.u[3] = cvt_pk_bf16(w1.z, w1.w);
                *reinterpret_cast<s8v*>(&Ws[(il * BN + o) * NDEG]) = pk.s;
            }
        }

        // ---- A stage: x -> tanh -> Chebyshev-U -> bf16 -> LDS ----
        {
            const float2 xv = *reinterpret_cast<const float2*>(xp + it * IPB);
            const float vv[2] = {xv.x, xv.y};
#pragma unroll
            for (int j = 0; j < 2; ++j) {
                const float t  = fast_tanh(vv[j]);
                const float t2 = t + t;
                const float c1 = t2;
                const float c2 = t2 * c1 - 1.0f;
                const float c3 = t2 * c2 - c1;
                const float c4 = t2 * c3 - c2;
                const float c5 = t2 * c4 - c3;
                const float c6 = t2 * c5 - c4;
                const float c7 = t2 * c6 - c5;
                union { s8v s; unsigned u[4]; } pk;
                pk.u[0] = cvt_pk_bf16(1.0f, c1);
                pk.u[1] = cvt_pk_bf16(c2, c3);
                pk.u[2] = cvt_pk_bf16(c4, c5);
                pk.u[3] = cvt_pk_bf16(c6, c7);
                *reinterpret_cast<s8v*>(&As[ar * LSTR + (ai + j) * NDEG]) = pk.s;
            }
        }
        __syncthreads();

        // ---- compute: ONE K=32 pass per wave (kh selects half), 4x4 mfma 16x16x32 ----
        {
            s8v afr[4], bfr[4];
#pragma unroll
            for (int tm = 0; tm < 4; ++tm)
                afr[tm] = *reinterpret_cast<const s8v*>(
                    &As[(tm * 16 + fm) * LSTR + kh * 32 + fq * 8]);
#pragma unroll
            for (int tn = 0; tn < 4; ++tn)
                bfr[tn] = *reinterpret_cast<const s8v*>(
                    &Ws[((kh * 4 + fq) * BN + wc + tn * 16 + fm) * NDEG]);
#pragma unroll
            for (int tm = 0; tm < 4; ++tm)
#pragma unroll
                for (int tn = 0; tn < 4; ++tn)
                    acc[tm][tn] = __builtin_amdgcn_mfma_f32_16x16x32_bf16(
                        afr[tm], bfr[tn], acc[tm][tn], 0, 0, 0);
        }
        __syncthreads();
    }

    // ---- epilogue: chunked pair-reduction (kh=1 pushes, kh=0 adds + stores) ----
    // C/D frag: col=fm, row=fq*4+r within each 16x16 tile at (tm*16, wc+tn*16).
#pragma unroll
    for (int tm = 0; tm < 4; ++tm) {
        if (kh == 1) {
#pragma unroll
            for (int tn = 0; tn < 4; ++tn)
#pragma unroll
                for (int r = 0; r < 4; ++r)
                    Rs[wave & 1][(fq * 4 + r) * 64 + tn * 16 + fm] = acc[tm][tn][r];
        }
        __syncthreads();
        if (kh == 0) {
#pragma unroll
            for (int tn = 0; tn < 4; ++tn) {
                const int row = bm0 + tm * 16 + fq * 4;
                const int col = bn0 + wc + tn * 16 + fm;
#pragma unroll
                for (int r = 0; r < 4; ++r)
                    out[(size_t)(row + r) * O_DIM + col] =
                        acc[tm][tn][r] + Rs[wave & 1][(fq * 4 + r) * 64 + tn * 16 + fm];
            }
        }
        __syncthreads();   // Rs reused next tm chunk
    }
}

extern "C" void kernel_launch(void* const* d_in, const int* in_sizes, int n_in,
                              void* d_out, int out_size, void* d_ws, size_t ws_size,
                              hipStream_t stream) {
    const float* x  = (const float*)d_in[0];
    const float* cf = (const float*)d_in[1];
    float* out = (float*)d_out;
    const int M = in_sizes[0] / I_DIM;            // 16384
    dim3 grid(O_DIM / BN, M / BM);                // (4, 256) = 1024 blocks
    dim3 block(NTHREADS, 1, 1);

    if (ws_size >= (size_t)W_ELEMS * sizeof(u16)) {
        u16* wbf = (u16*)d_ws;
        cvt_w<<<W_ELEMS / 1024, 256, 0, stream>>>(cf, wbf);
        gegen_gemm<true><<<grid, block, 0, stream>>>(x, cf, wbf, out);
    } else {
        gegen_gemm<false><<<grid, block, 0, stream>>>(x, cf, nullptr, out);
    }
}

// Round 4
// 159.911 us; speedup vs baseline: 1.1183x; 1.0090x over previous
//
#include <hip/hip_runtime.h>
#include <hip/hip_bf16.h>

// GegenbauerKAN layer == fused BF16-MFMA GEMM, M=16384 N=512 K=4096 (i*8+d).
// ALPHA=1 => Chebyshev-U recurrence: C_{n+1} = 2t*C_n - C_{n-1}, t = tanh(x).
// R2: coeffs pre-converted to bf16 in d_ws, W staged via global_load_lds(16B).
// R3 (REVERTED): explicit dbuf pipeline -6% (compiler already schedules).
// R4: BM=64 -> 4 blocks/CU; v_cvt_pk_bf16_f32 packing. (100us, VALU 30)
// R5: K-split waves, LDS reads -33%. (94us — small win; LDS not critical path)
// R6: BN 128->256 (grid (2,256)): feature redundancy 4x->2x — device feature
//     VALU halves; W L2 traffic unchanged (prop. to M/BM only). K-split dropped
//     (R5 showed its savings off-critical-path; frees LDS + kills epilogue
//     reduce). 4 waves of 32x128 (2x8 frags), LDS 42KB -> 3 blocks/CU.

#define I_DIM 512
#define O_DIM 512
#define NDEG 8
#define BM 64
#define BN 256
#define IPB 8              // i-values per K-iteration (BK = 64)
#define LSTR 72            // As row stride in bf16 elems (144 B)
#define KITERS (I_DIM / IPB)
#define NTHREADS 256
#define W_ELEMS (I_DIM * O_DIM * NDEG)   // 2,097,152

typedef __attribute__((ext_vector_type(8))) short s8v;    // MFMA A/B frag (8 bf16)
typedef __attribute__((ext_vector_type(4))) float f32x4;  // MFMA C/D frag
typedef unsigned short u16;

// HW packed f32->bf16 (RNE): D[15:0]=bf16(lo), D[31:16]=bf16(hi). 1 VALU op.
__device__ __forceinline__ unsigned cvt_pk_bf16(float lo, float hi) {
    unsigned r;
    asm("v_cvt_pk_bf16_f32 %0, %1, %2" : "=v"(r) : "v"(lo), "v"(hi));
    return r;
}

__device__ __forceinline__ float fast_tanh(float v) {
    float e = __expf(v + v);
    float r = __builtin_amdgcn_rcpf(e + 1.0f);
    return 1.0f - (r + r);
}

// ---- one-shot coeffs fp32 -> bf16 into workspace (re-run every call; ws is re-poisoned)
extern "C" __global__ __launch_bounds__(256)
void cvt_w(const float* __restrict__ cf, u16* __restrict__ wbf) {
    const size_t idx = ((size_t)blockIdx.x * 256 + threadIdx.x) * 4;
    const float4 v = *reinterpret_cast<const float4*>(cf + idx);
    unsigned* dst = reinterpret_cast<unsigned*>(wbf + idx);
    dst[0] = cvt_pk_bf16(v.x, v.y);
    dst[1] = cvt_pk_bf16(v.z, v.w);
}

template <bool PRECONV>
__global__ __launch_bounds__(NTHREADS, 3)
void gegen_gemm(const float* __restrict__ x,
                const float* __restrict__ cf,
                const u16* __restrict__ wbf,
                float* __restrict__ out)
{
    __shared__ u16 As[BM * LSTR];          // [m][k] bf16, padded rows (9.2 KB)
    __shared__ u16 Ws[IPB * BN * NDEG];    // [i_local][o][d] bf16, UNPADDED (32 KB, global_load_lds dst)

    const int tid  = threadIdx.x;
    const int lane = tid & 63;
    const int wave = tid >> 6;             // 0..3, 2x2 grid of 32x128 wave tiles
    const int fm   = lane & 15;
    const int fq   = lane >> 4;
    const int wr   = ((wave >> 1) & 1) << 5;  // 0 / 32
    const int wc   = (wave & 1) << 7;         // 0 / 128

    const int bm0 = blockIdx.y * BM;
    const int bn0 = blockIdx.x * BN;

    // A staging map: 64 rows x 8 i = 512 floats, one float2 per thread
    const int ar = tid >> 2;               // row 0..63
    const int ai = (tid & 3) << 1;         // i_local 0,2,4,6
    const float* xp = x + (size_t)(bm0 + ar) * I_DIM + ai;

    f32x4 acc[2][8];
#pragma unroll
    for (int a = 0; a < 2; ++a)
#pragma unroll
        for (int b = 0; b < 8; ++b)
            acc[a][b] = (f32x4){0.0f, 0.0f, 0.0f, 0.0f};

    for (int it = 0; it < KITERS; ++it) {
        // ---- W stage: 32 KiB tile ----
        if (PRECONV) {
            // 32 wave-chunks of 1 KiB; 8 chunks per wave.
            const u16* wsrc = wbf + ((size_t)(it * IPB) * O_DIM + bn0) * NDEG;
#pragma unroll
            for (int q = 0; q < 8; ++q) {
                const int c    = wave * 8 + q;   // 0..31
                const int il   = c >> 2;         // i_local 0..7
                const int qt   = c & 3;          // col quarter 0..3
                const u16* src = wsrc + ((size_t)il * O_DIM + qt * 64 + lane) * NDEG;
                u16* dst = &Ws[(il * BN + qt * 64) * NDEG];  // wave-uniform base
                __builtin_amdgcn_global_load_lds(
                    (const __attribute__((address_space(1))) void*)src,
                    (__attribute__((address_space(3))) void*)dst, 16, 0, 0);
            }
        } else {
            // fallback: VALU cvt staging (ws too small)
#pragma unroll
            for (int jj = 0; jj < 8; ++jj) {
                const int p  = jj * NTHREADS + tid;   // 0..2047
                const int il = p >> 8;
                const int o  = p & 255;
                const float* src = cf + ((size_t)(it * IPB + il) * O_DIM + bn0 + o) * NDEG;
                const float4 w0 = reinterpret_cast<const float4*>(src)[0];
                const float4 w1 = reinterpret_cast<const float4*>(src)[1];
                union { s8v s; unsigned u[4]; } pk;
                pk.u[0] = cvt_pk_bf16(w0.x, w0.y);
                pk.u[1] = cvt_pk_bf16(w0.z, w0.w);
                pk.u[2] = cvt_pk_bf16(w1.x, w1.y);
                pk.u[3] = cvt_pk_bf16(w1.z, w1.w);
                *reinterpret_cast<s8v*>(&Ws[(il * BN + o) * NDEG]) = pk.s;
            }
        }

        // ---- A stage: x -> tanh -> Chebyshev-U -> bf16 -> LDS ----
        {
            const float2 xv = *reinterpret_cast<const float2*>(xp + it * IPB);
            const float vv[2] = {xv.x, xv.y};
#pragma unroll
            for (int j = 0; j < 2; ++j) {
                const float t  = fast_tanh(vv[j]);
                const float t2 = t + t;
                const float c1 = t2;
                const float c2 = t2 * c1 - 1.0f;
                const float c3 = t2 * c2 - c1;
                const float c4 = t2 * c3 - c2;
                const float c5 = t2 * c4 - c3;
                const float c6 = t2 * c5 - c4;
                const float c7 = t2 * c6 - c5;
                union { s8v s; unsigned u[4]; } pk;
                pk.u[0] = cvt_pk_bf16(1.0f, c1);
                pk.u[1] = cvt_pk_bf16(c2, c3);
                pk.u[2] = cvt_pk_bf16(c4, c5);
                pk.u[3] = cvt_pk_bf16(c6, c7);
                *reinterpret_cast<s8v*>(&As[ar * LSTR + (ai + j) * NDEG]) = pk.s;
            }
        }
        __syncthreads();

        // ---- compute: 2 k-chunks of 32, 2x8 of mfma 16x16x32 per wave ----
#pragma unroll
        for (int kc = 0; kc < 2; ++kc) {
            s8v afr[2], bfr[8];
#pragma unroll
            for (int tm = 0; tm < 2; ++tm)
                afr[tm] = *reinterpret_cast<const s8v*>(
                    &As[(wr + tm * 16 + fm) * LSTR + kc * 32 + fq * 8]);
#pragma unroll
            for (int tn = 0; tn < 8; ++tn)
                bfr[tn] = *reinterpret_cast<const s8v*>(
                    &Ws[((kc * 4 + fq) * BN + wc + tn * 16 + fm) * NDEG]);
#pragma unroll
            for (int tm = 0; tm < 2; ++tm)
#pragma unroll
                for (int tn = 0; tn < 8; ++tn)
                    acc[tm][tn] = __builtin_amdgcn_mfma_f32_16x16x32_bf16(
                        afr[tm], bfr[tn], acc[tm][tn], 0, 0, 0);
        }
        __syncthreads();
    }

    // ---- epilogue: C/D col=lane&15, row=fq*4+reg ----
#pragma unroll
    for (int tm = 0; tm < 2; ++tm) {
#pragma unroll
        for (int tn = 0; tn < 8; ++tn) {
            const int row = bm0 + wr + tm * 16 + fq * 4;
            const int col = bn0 + wc + tn * 16 + fm;
#pragma unroll
            for (int r = 0; r < 4; ++r)
                out[(size_t)(row + r) * O_DIM + col] = acc[tm][tn][r];
        }
    }
}

extern "C" void kernel_launch(void* const* d_in, const int* in_sizes, int n_in,
                              void* d_out, int out_size, void* d_ws, size_t ws_size,
                              hipStream_t stream) {
    const float* x  = (const float*)d_in[0];
    const float* cf = (const float*)d_in[1];
    float* out = (float*)d_out;
    const int M = in_sizes[0] / I_DIM;            // 16384
    dim3 grid(O_DIM / BN, M / BM);                // (2, 256) = 512 blocks
    dim3 block(NTHREADS, 1, 1);

    if (ws_size >= (size_t)W_ELEMS * sizeof(u16)) {
        u16* wbf = (u16*)d_ws;
        cvt_w<<<W_ELEMS / 1024, 256, 0, stream>>>(cf, wbf);
        gegen_gemm<true><<<grid, block, 0, stream>>>(x, cf, wbf, out);
    } else {
        gegen_gemm<false><<<grid, block, 0, stream>>>(x, cf, nullptr, out);
    }
}